// Round 23
// baseline (195.000 us; speedup 1.0000x reference)
//
#include <hip/hip_runtime.h>
#include <hip/hip_bf16.h>

#define NGROUPS 8   // L=2 labels * S=4 sessions
#define DIM 128
#define WS_FLOATS 2056          // F: sums[8][128] wsums[8][128] counts[8]
#define NBLK 2048               // accum grid (4 waves each -> 8192 waves -> 1024 octets)

typedef float f32x4 __attribute__((ext_vector_type(4)));

// x + dpp(x): one step of a VALU-only wave reduction (no LDS pipe)
template <int CTRL>
__device__ __forceinline__ float dpp_add(float x) {
    int s = __builtin_amdgcn_update_dpp(0, __float_as_int(x), CTRL, 0xF, 0xF, true);
    return x + __int_as_float(s);
}

// per-32-lane-half sums (verified R4/R22): after shr1/2/4/8 + bcast15,
// lane31 = sum(lanes 0..31), lane63 = sum(lanes 32..63).
// Returns SGPR pair {1/max(||lo||,1e-8), 1/max(||hi||,1e-8)}.
__device__ __forceinline__ float2 pair_rnorm(float ss) {
    float r = ss;
    r = dpp_add<0x111>(r);  // row_shr:1
    r = dpp_add<0x112>(r);  // row_shr:2
    r = dpp_add<0x114>(r);  // row_shr:4
    r = dpp_add<0x118>(r);  // row_shr:8
    r = dpp_add<0x142>(r);  // row_bcast:15
    float inv = fminf(__builtin_amdgcn_rsqf(r), 1e8f);  // 1e8 == 1/eps cap
    float a = __int_as_float(__builtin_amdgcn_readlane(__float_as_int(inv), 31));
    float b = __int_as_float(__builtin_amdgcn_readlane(__float_as_int(inv), 63));
    return make_float2(a, b);
}

// extract up to 2 rows from mask M; lo half loads r1, hi half loads r2.
// If only one row remains, hi half re-loads r1 (same cache lines) and zeroes.
#define PAIRLOAD(V, M)                                                   \
    {                                                                    \
        int r1_ = __ffsll((long long)(M)) - 1; (M) &= (M) - 1;           \
        bool h2_ = ((M) != 0ull);                                        \
        int r2_ = r1_;                                                   \
        if (h2_) { r2_ = __ffsll((long long)(M)) - 1; (M) &= (M) - 1; }  \
        int row_ = (lane < 32) ? r1_ : r2_;                              \
        V = feat4[(size_t)(span + row_) * 32 + sub];                     \
        if (!h2_ && lane >= 32) V = zzz;                                 \
    }

// one 5-step DPP chain serves both rows; accumulate is unconditional
// (all processed rows belong to this wave's group q).
#define PAIRPROC(V)                                                      \
    {                                                                    \
        float ss_ = (V).x * (V).x + (V).y * (V).y                        \
                  + (V).z * (V).z + (V).w * (V).w;                       \
        float2 rr_ = pair_rnorm(ss_);                                    \
        float rn_ = (lane < 32) ? rr_.x : rr_.y;                         \
        sa0 += (V).x; sa1 += (V).y; sa2 += (V).z; sa3 += (V).w;          \
        wa0 = fmaf(rn_, (V).x, wa0); wa1 = fmaf(rn_, (V).y, wa1);        \
        wa2 = fmaf(rn_, (V).z, wa2); wa3 = fmaf(rn_, (V).w, wa3);        \
    }

// Wave-group specialization (R20) + float4/half-wave row pairing (R22)
// + DIRECT ATOMIC FLUSH into F (drops P partials, reduce kernel, and all
// LDS in accum; atomic-vs-store flush measured null in R13->R14).
__global__ __launch_bounds__(256, 8)
void csca_accum_kernel(const f32x4* __restrict__ feat4,
                       const int* __restrict__ labels,
                       const int* __restrict__ sessions,
                       float* __restrict__ F, int B) {
    const int lane = threadIdx.x & 63;
    const int sub = lane & 31;
    const int wid = __builtin_amdgcn_readfirstlane(blockIdx.x * 4 + (threadIdx.x >> 6));
    const int q = wid & 7;              // my group (wave-uniform)
    const int oct = wid >> 3;           // octet id
    const int NOCT = (gridDim.x * 4) >> 3;
    const int step = NOCT * 64;
    const f32x4 zzz = {0.0f, 0.0f, 0.0f, 0.0f};

    float sa0 = 0.0f, sa1 = 0.0f, sa2 = 0.0f, sa3 = 0.0f;
    float wa0 = 0.0f, wa1 = 0.0f, wa2 = 0.0f, wa3 = 0.0f;
    int cntq = 0;

    int span0 = oct * 64;
    if (span0 + 63 < B) {
        // prologue: current span's ids (cross-span prefetch kept from R21)
        int lb = labels[span0 + lane];
        int se = sessions[span0 + lane];

        for (int span = span0; span + 63 < B; span += step) {
            const int nspan = span + step;
            int nlb = 0, nse = 0;
            if (nspan + 63 < B) {
                nlb = labels[nspan + lane];
                nse = sessions[nspan + lane];
            }

            const int g = lb * 4 + se;
            unsigned long long m = __ballot(g == q);   // my rows in this span
            cntq += (int)__popcll(m);

            if (m != 0ull) {
                // depth-2 pipelined pair-scan
                f32x4 va, vb;
                PAIRLOAD(va, m);
                while (m != 0ull) {
                    PAIRLOAD(vb, m);    // prefetch next pair
                    PAIRPROC(va);
                    va = vb;
                }
                PAIRPROC(va);
            }

            lb = nlb; se = nse;
        }
    }

    // fold halves: lane l (<32) ends with dims [4l..4l+3] totals for group q
    sa0 += __shfl_xor(sa0, 32); sa1 += __shfl_xor(sa1, 32);
    sa2 += __shfl_xor(sa2, 32); sa3 += __shfl_xor(sa3, 32);
    wa0 += __shfl_xor(wa0, 32); wa1 += __shfl_xor(wa1, 32);
    wa2 += __shfl_xor(wa2, 32); wa3 += __shfl_xor(wa3, 32);

    // direct atomic flush: 8 atomics/thread (lane<32) to distinct (q,dim)
    // addresses; ~1024 contenders/address — measured-free scale (R14).
    if (lane < 32) {
        float* Fs = F + q * DIM + 4 * lane;
        atomicAdd(Fs + 0, sa0); atomicAdd(Fs + 1, sa1);
        atomicAdd(Fs + 2, sa2); atomicAdd(Fs + 3, sa3);
        float* Fw = F + 1024 + q * DIM + 4 * lane;
        atomicAdd(Fw + 0, wa0); atomicAdd(Fw + 1, wa1);
        atomicAdd(Fw + 2, wa2); atomicAdd(Fw + 3, wa3);
    }
    if (lane == 0) atomicAdd(&F[2048 + q], (float)cntq);
}

__global__ __launch_bounds__(256)
void csca_finalize_kernel(const float* __restrict__ F, float* __restrict__ out, float invB) {
    __shared__ float red[WS_FLOATS];
    for (int i = threadIdx.x; i < WS_FLOATS; i += 256) red[i] = F[i];
    __syncthreads();

    if (threadIdx.x < 64) {
        const int lane = threadIdx.x;
        const float* sums  = red;
        const float* wsums = red + 1024;
        const float* cnts  = red + 2048;
        __shared__ float c_lds[NGROUPS][DIM];
        float cnorm2[NGROUPS];
        float cos_sum = 0.0f;

#pragma unroll
        for (int g = 0; g < NGROUPS; ++g) {
            float invc = 1.0f / cnts[g];
            float c0 = sums[g * DIM + lane] * invc;
            float c1 = sums[g * DIM + 64 + lane] * invc;
            c_lds[g][lane] = c0;
            c_lds[g][64 + lane] = c1;
            float w0 = wsums[g * DIM + lane];
            float w1 = wsums[g * DIM + 64 + lane];
            float pcc = c0 * c0 + c1 * c1;
            float pwc = w0 * c0 + w1 * c1;
#pragma unroll
            for (int m = 1; m < 64; m <<= 1) {
                pcc += __shfl_xor(pcc, m);
                pwc += __shfl_xor(pwc, m);
            }
            cnorm2[g] = pcc;
            cos_sum += pwc / fmaxf(sqrtf(pcc), 1e-8f);
        }
        float center_loss = 1.0f - cos_sum * invB;

        float align = 0.0f;
#pragma unroll
        for (int y = 0; y < 2; ++y) {
            float p0 = 0.0f, p1 = 0.0f;
#pragma unroll
            for (int s = 0; s < 4; ++s) {
                p0 += c_lds[4 * y + s][lane];
                p1 += c_lds[4 * y + s][64 + lane];
            }
            p0 *= 0.25f; p1 *= 0.25f;
            float ppp = p0 * p0 + p1 * p1;
#pragma unroll
            for (int m = 1; m < 64; m <<= 1) ppp += __shfl_xor(ppp, m);
            float pn = fmaxf(sqrtf(ppp), 1e-8f);
            float pc = 0.0f;
#pragma unroll
            for (int s = 0; s < 4; ++s) {
                float d = c_lds[4 * y + s][lane] * p0 + c_lds[4 * y + s][64 + lane] * p1;
#pragma unroll
                for (int m = 1; m < 64; m <<= 1) d += __shfl_xor(d, m);
                float cs = d / (fmaxf(sqrtf(cnorm2[4 * y + s]), 1e-8f) * pn);
                pc += 1.0f - cs;
            }
            align = (align + pc) * 0.25f;  // running /S division, faithful to reference
        }

        if (lane == 0) {
            out[0] = center_loss + align;
            out[1] = center_loss;
            out[2] = align;
        }
    }
}

extern "C" void kernel_launch(void* const* d_in, const int* in_sizes, int n_in,
                              void* d_out, int out_size, void* d_ws, size_t ws_size,
                              hipStream_t stream) {
    const float* feat = (const float*)d_in[0];
    const int* labels = (const int*)d_in[1];
    const int* sessions = (const int*)d_in[2];
    const int B = in_sizes[1];          // 1048576 (features are B x 128)
    float* F = (float*)d_ws;

    hipMemsetAsync(F, 0, WS_FLOATS * sizeof(float), stream);

    csca_accum_kernel<<<NBLK, 256, 0, stream>>>((const f32x4*)feat, labels, sessions, F, B);
    csca_finalize_kernel<<<1, 256, 0, stream>>>(F, (float*)d_out, 1.0f / (float)B);
}

// Round 24
// 121.025 us; speedup vs baseline: 1.6112x; 1.6112x over previous
//
#include <hip/hip_runtime.h>
#include <hip/hip_bf16.h>

#define NGROUPS 8   // L=2 labels * S=4 sessions
#define DIM 128
#define WS_FLOATS 2056          // per-block partial: sums[8][128] wsums[8][128] counts[8]
#define NBLK 2048               // accum grid (4 waves each -> 8192 waves -> 1024 octets)
// workspace: P[NBLK][WS_FLOATS] partials, then F[WS_FLOATS] finals
#define F_OFFSET ((size_t)NBLK * WS_FLOATS)

typedef float f32x4 __attribute__((ext_vector_type(4)));

// x + dpp(x): one step of a VALU-only wave reduction (no LDS pipe)
template <int CTRL>
__device__ __forceinline__ float dpp_add(float x) {
    int s = __builtin_amdgcn_update_dpp(0, __float_as_int(x), CTRL, 0xF, 0xF, true);
    return x + __int_as_float(s);
}

// per-32-lane-half sums (verified R4/R22): after shr1/2/4/8 + bcast15,
// lane31 = sum(lanes 0..31), lane63 = sum(lanes 32..63).
// Returns SGPR pair {1/max(||lo||,1e-8), 1/max(||hi||,1e-8)}.
__device__ __forceinline__ float2 pair_rnorm(float ss) {
    float r = ss;
    r = dpp_add<0x111>(r);  // row_shr:1
    r = dpp_add<0x112>(r);  // row_shr:2
    r = dpp_add<0x114>(r);  // row_shr:4
    r = dpp_add<0x118>(r);  // row_shr:8
    r = dpp_add<0x142>(r);  // row_bcast:15
    float inv = fminf(__builtin_amdgcn_rsqf(r), 1e8f);  // 1e8 == 1/eps cap
    float a = __int_as_float(__builtin_amdgcn_readlane(__float_as_int(inv), 31));
    float b = __int_as_float(__builtin_amdgcn_readlane(__float_as_int(inv), 63));
    return make_float2(a, b);
}

// extract up to 2 rows from mask M; lo half loads r1, hi half loads r2.
// If only one row remains, hi half is zeroed (contributes nothing).
#define PAIRLOAD(V, M)                                                   \
    {                                                                    \
        int r1_ = __ffsll((long long)(M)) - 1; (M) &= (M) - 1;           \
        bool h2_ = ((M) != 0ull);                                        \
        int r2_ = r1_;                                                   \
        if (h2_) { r2_ = __ffsll((long long)(M)) - 1; (M) &= (M) - 1; }  \
        int row_ = (lane < 32) ? r1_ : r2_;                              \
        V = feat4[(size_t)(span + row_) * 32 + sub];                     \
        if (!h2_ && lane >= 32) V = zzz;                                 \
    }

// one 5-step DPP chain serves both rows; accumulate is unconditional
// (all processed rows belong to this wave's group q).
#define PAIRPROC(V)                                                      \
    {                                                                    \
        float ss_ = (V).x * (V).x + (V).y * (V).y                        \
                  + (V).z * (V).z + (V).w * (V).w;                       \
        float2 rr_ = pair_rnorm(ss_);                                    \
        float rn_ = (lane < 32) ? rr_.x : rr_.y;                         \
        sa0 += (V).x; sa1 += (V).y; sa2 += (V).z; sa3 += (V).w;          \
        wa0 = fmaf(rn_, (V).x, wa0); wa1 = fmaf(rn_, (V).y, wa1);        \
        wa2 = fmaf(rn_, (V).z, wa2); wa3 = fmaf(rn_, (V).w, wa3);        \
    }

// Wave-group specialization (R20) + float4/half-wave ROW PAIRING (R22):
// one load instr + one DPP chain per TWO rows. Accumulator = 8 scalars.
__global__ __launch_bounds__(256, 8)
void csca_accum_kernel(const f32x4* __restrict__ feat4,
                       const int* __restrict__ labels,
                       const int* __restrict__ sessions,
                       float* __restrict__ gws, int B) {
    __shared__ float s_all[WS_FLOATS];
    for (int i = threadIdx.x; i < WS_FLOATS; i += 256) s_all[i] = 0.0f;
    __syncthreads();

    const int lane = threadIdx.x & 63;
    const int sub = lane & 31;
    const int wid = __builtin_amdgcn_readfirstlane(blockIdx.x * 4 + (threadIdx.x >> 6));
    const int q = wid & 7;              // my group (wave-uniform)
    const int oct = wid >> 3;           // octet id
    const int NOCT = (gridDim.x * 4) >> 3;
    const int step = NOCT * 64;
    const f32x4 zzz = {0.0f, 0.0f, 0.0f, 0.0f};

    float sa0 = 0.0f, sa1 = 0.0f, sa2 = 0.0f, sa3 = 0.0f;
    float wa0 = 0.0f, wa1 = 0.0f, wa2 = 0.0f, wa3 = 0.0f;
    int cntq = 0;

    int span0 = oct * 64;
    if (span0 + 63 < B) {
        // prologue: current span's ids (cross-span prefetch kept from R21)
        int lb = labels[span0 + lane];
        int se = sessions[span0 + lane];

        for (int span = span0; span + 63 < B; span += step) {
            const int nspan = span + step;
            int nlb = 0, nse = 0;
            if (nspan + 63 < B) {
                nlb = labels[nspan + lane];
                nse = sessions[nspan + lane];
            }

            const int g = lb * 4 + se;
            unsigned long long m = __ballot(g == q);   // my rows in this span
            cntq += (int)__popcll(m);

            if (m != 0ull) {
                // depth-2 pipelined pair-scan
                f32x4 va, vb;
                PAIRLOAD(va, m);
                while (m != 0ull) {
                    PAIRLOAD(vb, m);    // prefetch next pair
                    PAIRPROC(va);
                    va = vb;
                }
                PAIRPROC(va);
            }

            lb = nlb; se = nse;
        }
    }

    // fold halves: lane l (<32) ends with dims [4l..4l+3] totals for group q
    sa0 += __shfl_xor(sa0, 32); sa1 += __shfl_xor(sa1, 32);
    sa2 += __shfl_xor(sa2, 32); sa3 += __shfl_xor(sa3, 32);
    wa0 += __shfl_xor(wa0, 32); wa1 += __shfl_xor(wa1, 32);
    wa2 += __shfl_xor(wa2, 32); wa3 += __shfl_xor(wa3, 32);

    // epilogue: within a block the 4 waves have DISTINCT groups -> plain stores
    if (lane < 32) {
        s_all[q * DIM + 4 * lane]     = sa0;
        s_all[q * DIM + 4 * lane + 1] = sa1;
        s_all[q * DIM + 4 * lane + 2] = sa2;
        s_all[q * DIM + 4 * lane + 3] = sa3;
        s_all[1024 + q * DIM + 4 * lane]     = wa0;
        s_all[1024 + q * DIM + 4 * lane + 1] = wa1;
        s_all[1024 + q * DIM + 4 * lane + 2] = wa2;
        s_all[1024 + q * DIM + 4 * lane + 3] = wa3;
    }
    if (lane == 0) s_all[2048 + q] = (float)cntq;
    __syncthreads();

    // NON-ATOMIC coalesced store of this block's partials
    float* myP = gws + (size_t)blockIdx.x * WS_FLOATS;
    for (int i = threadIdx.x; i < WS_FLOATS; i += 256) myP[i] = s_all[i];
}

// parallel fold of the NBLK partial vectors: grid (9, 32); block (x) covers
// 256 elements, block (y) covers 64 replicas; 32 atomics/address total.
__global__ __launch_bounds__(256)
void csca_reduce_kernel(const float* __restrict__ gws, float* __restrict__ F) {
    const int i = blockIdx.x * 256 + threadIdx.x;
    if (i >= WS_FLOATS) return;
    const int r0 = blockIdx.y * (NBLK / 32);
    float s = 0.0f;
#pragma unroll 8
    for (int k = 0; k < NBLK / 32; ++k)
        s += gws[(size_t)(r0 + k) * WS_FLOATS + i];
    atomicAdd(&F[i], s);
}

__global__ __launch_bounds__(256)
void csca_finalize_kernel(const float* __restrict__ F, float* __restrict__ out, float invB) {
    __shared__ float red[WS_FLOATS];
    for (int i = threadIdx.x; i < WS_FLOATS; i += 256) red[i] = F[i];
    __syncthreads();

    if (threadIdx.x < 64) {
        const int lane = threadIdx.x;
        const float* sums  = red;
        const float* wsums = red + 1024;
        const float* cnts  = red + 2048;
        __shared__ float c_lds[NGROUPS][DIM];
        float cnorm2[NGROUPS];
        float cos_sum = 0.0f;

#pragma unroll
        for (int g = 0; g < NGROUPS; ++g) {
            float invc = 1.0f / cnts[g];
            float c0 = sums[g * DIM + lane] * invc;
            float c1 = sums[g * DIM + 64 + lane] * invc;
            c_lds[g][lane] = c0;
            c_lds[g][64 + lane] = c1;
            float w0 = wsums[g * DIM + lane];
            float w1 = wsums[g * DIM + 64 + lane];
            float pcc = c0 * c0 + c1 * c1;
            float pwc = w0 * c0 + w1 * c1;
#pragma unroll
            for (int m = 1; m < 64; m <<= 1) {
                pcc += __shfl_xor(pcc, m);
                pwc += __shfl_xor(pwc, m);
            }
            cnorm2[g] = pcc;
            cos_sum += pwc / fmaxf(sqrtf(pcc), 1e-8f);
        }
        float center_loss = 1.0f - cos_sum * invB;

        float align = 0.0f;
#pragma unroll
        for (int y = 0; y < 2; ++y) {
            float p0 = 0.0f, p1 = 0.0f;
#pragma unroll
            for (int s = 0; s < 4; ++s) {
                p0 += c_lds[4 * y + s][lane];
                p1 += c_lds[4 * y + s][64 + lane];
            }
            p0 *= 0.25f; p1 *= 0.25f;
            float ppp = p0 * p0 + p1 * p1;
#pragma unroll
            for (int m = 1; m < 64; m <<= 1) ppp += __shfl_xor(ppp, m);
            float pn = fmaxf(sqrtf(ppp), 1e-8f);
            float pc = 0.0f;
#pragma unroll
            for (int s = 0; s < 4; ++s) {
                float d = c_lds[4 * y + s][lane] * p0 + c_lds[4 * y + s][64 + lane] * p1;
#pragma unroll
                for (int m = 1; m < 64; m <<= 1) d += __shfl_xor(d, m);
                float cs = d / (fmaxf(sqrtf(cnorm2[4 * y + s]), 1e-8f) * pn);
                pc += 1.0f - cs;
            }
            align = (align + pc) * 0.25f;  // running /S division, faithful to reference
        }

        if (lane == 0) {
            out[0] = center_loss + align;
            out[1] = center_loss;
            out[2] = align;
        }
    }
}

extern "C" void kernel_launch(void* const* d_in, const int* in_sizes, int n_in,
                              void* d_out, int out_size, void* d_ws, size_t ws_size,
                              hipStream_t stream) {
    const float* feat = (const float*)d_in[0];
    const int* labels = (const int*)d_in[1];
    const int* sessions = (const int*)d_in[2];
    const int B = in_sizes[1];          // 1048576 (features are B x 128)
    float* gws = (float*)d_ws;
    float* F = gws + F_OFFSET;

    // only the small final vector needs zeroing (reduce uses atomicAdd on it)
    hipMemsetAsync(F, 0, WS_FLOATS * sizeof(float), stream);

    csca_accum_kernel<<<NBLK, 256, 0, stream>>>((const f32x4*)feat, labels, sessions, gws, B);
    csca_reduce_kernel<<<dim3(9, 32), 256, 0, stream>>>(gws, F);
    csca_finalize_kernel<<<1, 256, 0, stream>>>(F, (float*)d_out, 1.0f / (float)B);
}